// Round 1
// baseline (199.377 us; speedup 1.0000x reference)
//
#include <hip/hip_runtime.h>
#include <hip/hip_bf16.h>

#define B_ 4
#define N_ 4096
#define L_ 4104
#define D_ 512
#define CH 513
#define JC 8
#define RT 17

typedef __attribute__((ext_vector_type(8))) short bf16x8;
typedef __attribute__((ext_vector_type(4))) float f32x4;

#define AS1(p) ((__attribute__((address_space(1))) const void*)(p))
#define AS3(p) ((__attribute__((address_space(3))) void*)(p))

// ---------------- K0: proj_w f32 -> bf16 ----------------
__global__ __launch_bounds__(256) void k_cvt(const float* __restrict__ src,
                                             __hip_bfloat16* __restrict__ dst) {
  int i = blockIdx.x * 256 + threadIdx.x;   // grid covers 512*512 exactly
  dst[i] = __float2bfloat16(src[i]);
}

// ---------------- K1: embedding gather + depthwise conv -> y (bf16) ----------------
__global__ __launch_bounds__(256) void k_embconv(const int* __restrict__ x,
    const float* __restrict__ emb, const float* __restrict__ conv_w,
    const float* __restrict__ conv_b, unsigned* __restrict__ y) {
  const int row = blockIdx.x;              // b*N_ + i
  const int b = row >> 12, i = row & (N_ - 1);
  const int t = threadIdx.x;
  const int d = t * 2;
  const float4 c0 = ((const float4*)conv_w)[d];
  const float4 c1 = ((const float4*)conv_w)[d + 1];
  const float ca[4] = {c0.x, c0.y, c0.z, c0.w};
  const float cb[4] = {c1.x, c1.y, c1.z, c1.w};
  float2 acc = ((const float2*)conv_b)[t];
#pragma unroll
  for (int k = 0; k < 4; ++k) {
    if (i + k < N_) {
      const int tok = x[b * N_ + i + k];
      const float2 e = *(const float2*)(emb + (size_t)tok * D_ + d);
      acc.x += e.x * ca[k];
      acc.y += e.y * cb[k];
    }
  }
  union { __hip_bfloat16 h[2]; unsigned u; } pk;
  pk.h[0] = __float2bfloat16(acc.x);
  pk.h[1] = __float2bfloat16(acc.y);
  y[(size_t)row * 256 + t] = pk.u;
}

// ---------------- K2: h = y @ proj_w^T + proj_b  (bf16 MFMA, f32 out) ----------------
__global__ __launch_bounds__(256) void k_gemm(const __hip_bfloat16* __restrict__ A,
    const __hip_bfloat16* __restrict__ W, const float* __restrict__ bias,
    float* __restrict__ C) {
  __shared__ __align__(16) __hip_bfloat16 As[128 * 32];
  __shared__ __align__(16) __hip_bfloat16 Bs[128 * 32];
  const int t = threadIdx.x;
  const int m0 = blockIdx.x * 128, n0 = blockIdx.y * 128;
  const int w = t >> 6, l = t & 63;
  const int quad = l >> 4, r16 = l & 15;
  const int wr = (w >> 1) * 64, wc = (w & 1) * 64;

  f32x4 acc[4][4];
#pragma unroll
  for (int a = 0; a < 4; ++a)
#pragma unroll
    for (int bq = 0; bq < 4; ++bq) acc[a][bq] = (f32x4){0.f, 0.f, 0.f, 0.f};

  const int srow = t >> 2;                 // staging row (q=0); q=1 adds 64
  const int scol = (t & 3) * 8;            // k offset within BK=32
  const int ldsb = (t & 192) * 16;         // wave-uniform LDS byte base (q=0); q=1 adds 4096

#pragma unroll 1
  for (int kt = 0; kt < 16; ++kt) {
    const int kb = kt * 32;
    __builtin_amdgcn_global_load_lds(AS1(A + ((size_t)(m0 + srow)) * 512 + kb + scol),
                                     AS3((char*)As + ldsb), 16, 0, 0);
    __builtin_amdgcn_global_load_lds(AS1(A + ((size_t)(m0 + 64 + srow)) * 512 + kb + scol),
                                     AS3((char*)As + 4096 + ldsb), 16, 0, 0);
    __builtin_amdgcn_global_load_lds(AS1(W + ((size_t)(n0 + srow)) * 512 + kb + scol),
                                     AS3((char*)Bs + ldsb), 16, 0, 0);
    __builtin_amdgcn_global_load_lds(AS1(W + ((size_t)(n0 + 64 + srow)) * 512 + kb + scol),
                                     AS3((char*)Bs + 4096 + ldsb), 16, 0, 0);
    __syncthreads();

    bf16x8 af[4], bf[4];
#pragma unroll
    for (int ti = 0; ti < 4; ++ti)
      af[ti] = *(const bf16x8*)(As + (wr + ti * 16 + r16) * 32 + quad * 8);
#pragma unroll
    for (int tj = 0; tj < 4; ++tj)
      bf[tj] = *(const bf16x8*)(Bs + (wc + tj * 16 + r16) * 32 + quad * 8);
#pragma unroll
    for (int ti = 0; ti < 4; ++ti)
#pragma unroll
      for (int tj = 0; tj < 4; ++tj)
        acc[ti][tj] = __builtin_amdgcn_mfma_f32_16x16x32_bf16(af[ti], bf[tj], acc[ti][tj], 0, 0, 0);
    __syncthreads();
  }

#pragma unroll
  for (int ti = 0; ti < 4; ++ti) {
    const int gi0 = m0 + wr + ti * 16 + quad * 4;
#pragma unroll
    for (int tj = 0; tj < 4; ++tj) {
      const int go = n0 + wc + tj * 16 + r16;
      const float bv = bias[go];
#pragma unroll
      for (int r = 0; r < 4; ++r)
        C[(size_t)(gi0 + r) * 512 + go] = acc[ti][tj][r] + bv;
    }
  }
}

// ---------------- K3: t[b,i] = h[b,i,:] . score_w ----------------
__global__ __launch_bounds__(256) void k_tdot(const float* __restrict__ h,
    const float* __restrict__ sw, float* __restrict__ tbuf) {
  const int w = threadIdx.x >> 6, l = threadIdx.x & 63;
  const int rr = blockIdx.x * 4 + w;       // 0..16415
  const int b = rr / L_, i = rr % L_;
  float s = 0.f;
  if (i < N_) {
    const float4* hr = (const float4*)(h + ((size_t)b * N_ + i) * D_);
    const float4* sw4 = (const float4*)sw;
    const float4 a0 = hr[l * 2],     a1 = hr[l * 2 + 1];
    const float4 w0 = sw4[l * 2],    w1 = sw4[l * 2 + 1];
    s = a0.x * w0.x + a0.y * w0.y + a0.z * w0.z + a0.w * w0.w
      + a1.x * w1.x + a1.y * w1.y + a1.z * w1.z + a1.w * w1.w;
  }
#pragma unroll
  for (int off = 32; off > 0; off >>= 1) s += __shfl_down(s, off);
  if (l == 0) tbuf[rr] = s;
}

// ---------------- K4: per-position 4-way softmax scores ----------------
__global__ __launch_bounds__(256) void k_scores(const float* __restrict__ tbuf,
    const float* __restrict__ sb, float4* __restrict__ S) {
  const int idx = blockIdx.x * 256 + threadIdx.x;
  if (idx >= B_ * L_) return;
  const int b = idx / L_, i = idx % L_;
  const float* tb = tbuf + b * L_;
  const float bb = sb[0];
  const float s0 = tb[i] + bb;
  const int j2 = i & ~1;
  const float s1 = (tb[j2] + tb[j2 + 1]) * 0.5f + bb;
  const int j3 = (i / 3) * 3;
  const float s2 = (tb[j3] + tb[j3 + 1] + tb[j3 + 2]) * (1.f / 3.f) + bb;
  const int j4 = i & ~3;
  const float s3 = (tb[j4] + tb[j4 + 1] + tb[j4 + 2] + tb[j4 + 3]) * 0.25f + bb;
  const float m = fmaxf(fmaxf(s0, s1), fmaxf(s2, s3));
  const float e0 = __expf(s0 - m), e1 = __expf(s1 - m), e2 = __expf(s2 - m), e3 = __expf(s3 - m);
  const float inv = 1.f / (e0 + e1 + e2 + e3);
  S[idx] = make_float4(e0 * inv, e1 * inv, e2 * inv, e3 * inv);
}

// ---------------- K5: zero accumulators ----------------
__global__ __launch_bounds__(256) void k_zero(float* __restrict__ p, int n) {
  const int i = blockIdx.x * 256 + threadIdx.x;
  if (i < n) p[i] = 0.f;
}

// ---------------- K6: consensus attention (flash-style, j-chunked + atomics) ----------------
__global__ __launch_bounds__(256) void k_attn(const float4* __restrict__ S,
    float* __restrict__ accn, float* __restrict__ accd) {
  __shared__ __align__(16) float4 Sch[CH];
  const int bx = blockIdx.x;
  const int jc = bx & (JC - 1);
  const int rt = (bx >> 3) % RT;
  const int b  = bx / (JC * RT);
  const int t = threadIdx.x;
  const float4* Sb = S + (size_t)b * L_;
  const int j0 = jc * CH;
  for (int idx = t; idx < CH; idx += 256) Sch[idx] = Sb[j0 + idx];
  __syncthreads();
  const int i = rt * 256 + t;
  if (i < L_) {
    const float4 si = Sb[i];
    float l = 0.f, a0 = 0.f, a1 = 0.f, a2 = 0.f, a3 = 0.f;
    for (int jj = 0; jj < CH; ++jj) {
      const float4 v = Sch[jj];
      const float dot = si.x * v.x + si.y * v.y + si.z * v.z + si.w * v.w;
      const float e = __expf(dot);   // dot in (0,1]; no max-shift needed
      l += e;
      a0 += e * v.x; a1 += e * v.y; a2 += e * v.z; a3 += e * v.w;
    }
    const int base = b * L_ + i;
    atomicAdd(&accd[base], l);
    atomicAdd(&accn[base * 4 + 0], a0);
    atomicAdd(&accn[base * 4 + 1], a1);
    atomicAdd(&accn[base * 4 + 2], a2);
    atomicAdd(&accn[base * 4 + 3], a3);
  }
}

// ---------------- K7: fuse block reprs (inline pooling) + downsample ----------------
__global__ __launch_bounds__(256) void k_fuse(const float* __restrict__ h,
    const float* __restrict__ accn, const float* __restrict__ accd,
    float* __restrict__ out) {
  const int b = blockIdx.x >> 10, j = blockIdx.x & 1023;
  const int t = threadIdx.x, d = t * 2;
  const int i0 = 4 * j;
  float wgt[4][4];
#pragma unroll
  for (int r = 0; r < 4; ++r) {
    const int gi = b * L_ + i0 + r;
    const float inv = 1.f / accd[gi];
#pragma unroll
    for (int k = 0; k < 4; ++k) wgt[r][k] = accn[gi * 4 + k] * inv;
  }
  const float* hb = h + (size_t)b * N_ * D_;
  float2 hv[4];
#pragma unroll
  for (int q = 0; q < 4; ++q)
    hv[q] = *(const float2*)(hb + (size_t)(i0 + q) * D_ + d);

  float2 p4;
  p4.x = (hv[0].x + hv[1].x + hv[2].x + hv[3].x) * 0.25f;
  p4.y = (hv[0].y + hv[1].y + hv[2].y + hv[3].y) * 0.25f;

  float ox = 0.f, oy = 0.f;
#pragma unroll
  for (int r = 0; r < 4; ++r) {
    const int i = i0 + r;
    const float2 p1 = hv[r];
    const int b2 = r & ~1;
    float2 p2;
    p2.x = (hv[b2].x + hv[b2 + 1].x) * 0.5f;
    p2.y = (hv[b2].y + hv[b2 + 1].y) * 0.5f;
    const int r3 = (i / 3) * 3;            // block-uniform; rows r3..r3+2, zero past N_
    float2 p3 = make_float2(0.f, 0.f);
    for (int q = 0; q < 3; ++q) {
      const int row = r3 + q;
      if (row < N_) {
        const float2 e = *(const float2*)(hb + (size_t)row * D_ + d);
        p3.x += e.x; p3.y += e.y;
      }
    }
    p3.x *= (1.f / 3.f); p3.y *= (1.f / 3.f);
    ox += wgt[r][0] * p1.x + wgt[r][1] * p2.x + wgt[r][2] * p3.x + wgt[r][3] * p4.x;
    oy += wgt[r][0] * p1.y + wgt[r][1] * p2.y + wgt[r][2] * p3.y + wgt[r][3] * p4.y;
  }
  float2 o; o.x = ox * 0.25f; o.y = oy * 0.25f;
  *(float2*)(out + (size_t)(b * 1024 + j) * D_ + d) = o;
}

extern "C" void kernel_launch(void* const* d_in, const int* in_sizes, int n_in,
                              void* d_out, int out_size, void* d_ws, size_t ws_size,
                              hipStream_t stream) {
  const int*   x       = (const int*)d_in[0];
  const float* emb     = (const float*)d_in[1];
  const float* conv_w  = (const float*)d_in[2];
  const float* conv_b  = (const float*)d_in[3];
  const float* proj_w  = (const float*)d_in[4];
  const float* proj_b  = (const float*)d_in[5];
  const float* score_w = (const float*)d_in[6];
  const float* score_b = (const float*)d_in[7];
  float* out = (float*)d_out;

  char* ws = (char*)d_ws;
  size_t off = 0;
  __hip_bfloat16* Wbf = (__hip_bfloat16*)(ws + off); off += (size_t)512 * 512 * 2;
  unsigned*       y   = (unsigned*)(ws + off);       off += (size_t)16384 * 512 * 2;
  float*          h   = (float*)(ws + off);          off += (size_t)16384 * 512 * 4;
  float*          tb  = (float*)(ws + off);          off += (size_t)B_ * L_ * 4;
  float4*         S   = (float4*)(ws + off);         off += (size_t)B_ * L_ * 16;
  float*          accn = (float*)(ws + off);         off += (size_t)B_ * L_ * 4 * 4;
  float*          accd = (float*)(ws + off);         off += (size_t)B_ * L_ * 4;
  (void)in_sizes; (void)n_in; (void)out_size; (void)ws_size;

  k_cvt<<<1024, 256, 0, stream>>>(proj_w, Wbf);
  k_embconv<<<B_ * N_, 256, 0, stream>>>(x, emb, conv_w, conv_b, y);
  k_gemm<<<dim3(128, 4), 256, 0, stream>>>((const __hip_bfloat16*)y, Wbf, proj_b, h);
  k_tdot<<<(B_ * L_) / 4, 256, 0, stream>>>(h, score_w, tb);
  k_scores<<<(B_ * L_ + 255) / 256, 256, 0, stream>>>(tb, score_b, S);
  k_zero<<<(B_ * L_ * 5 + 255) / 256, 256, 0, stream>>>(accn, B_ * L_ * 5);
  k_attn<<<B_ * RT * JC, 256, 0, stream>>>(S, accn, accd);
  k_fuse<<<B_ * 1024, 256, 0, stream>>>(h, accn, accd, out);
}

// Round 2
// 174.311 us; speedup vs baseline: 1.1438x; 1.1438x over previous
//
#include <hip/hip_runtime.h>
#include <hip/hip_bf16.h>

#define B_ 4
#define N_ 4096
#define L_ 4104
#define D_ 512
#define RT 17
#define JC2 32
#define CH2 129

typedef __attribute__((ext_vector_type(8))) short bf16x8;
typedef __attribute__((ext_vector_type(4))) float f32x4;

#define AS1(p) ((__attribute__((address_space(1))) const void*)(p))
#define AS3(p) ((__attribute__((address_space(3))) void*)(p))

// ---------------- K0: proj_w f32 -> bf16 ----------------
__global__ __launch_bounds__(256) void k_cvt(const float* __restrict__ src,
                                             __hip_bfloat16* __restrict__ dst) {
  int i = blockIdx.x * 256 + threadIdx.x;   // grid covers 512*512 exactly
  dst[i] = __float2bfloat16(src[i]);
}

// ---------------- K1: embedding gather + depthwise conv -> y (bf16) ----------------
__global__ __launch_bounds__(256) void k_embconv(const int* __restrict__ x,
    const float* __restrict__ emb, const float* __restrict__ conv_w,
    const float* __restrict__ conv_b, unsigned* __restrict__ y) {
  const int row = blockIdx.x;              // b*N_ + i
  const int b = row >> 12, i = row & (N_ - 1);
  const int t = threadIdx.x;
  const int d = t * 2;
  const float4 c0 = ((const float4*)conv_w)[d];
  const float4 c1 = ((const float4*)conv_w)[d + 1];
  const float ca[4] = {c0.x, c0.y, c0.z, c0.w};
  const float cb[4] = {c1.x, c1.y, c1.z, c1.w};
  float2 acc = ((const float2*)conv_b)[t];
#pragma unroll
  for (int k = 0; k < 4; ++k) {
    if (i + k < N_) {
      const int tok = x[b * N_ + i + k];
      const float2 e = *(const float2*)(emb + (size_t)tok * D_ + d);
      acc.x += e.x * ca[k];
      acc.y += e.y * cb[k];
    }
  }
  union { __hip_bfloat16 h[2]; unsigned u; } pk;
  pk.h[0] = __float2bfloat16(acc.x);
  pk.h[1] = __float2bfloat16(acc.y);
  y[(size_t)row * 256 + t] = pk.u;
}

// ---------------- K2: h = y @ proj_w^T + proj_b  (bf16 MFMA, f32 out) ----------------
__global__ __launch_bounds__(256) void k_gemm(const __hip_bfloat16* __restrict__ A,
    const __hip_bfloat16* __restrict__ W, const float* __restrict__ bias,
    float* __restrict__ C) {
  __shared__ __align__(16) __hip_bfloat16 As[128 * 32];
  __shared__ __align__(16) __hip_bfloat16 Bs[128 * 32];
  const int t = threadIdx.x;
  const int m0 = blockIdx.x * 128, n0 = blockIdx.y * 128;
  const int w = t >> 6, l = t & 63;
  const int quad = l >> 4, r16 = l & 15;
  const int wr = (w >> 1) * 64, wc = (w & 1) * 64;

  f32x4 acc[4][4];
#pragma unroll
  for (int a = 0; a < 4; ++a)
#pragma unroll
    for (int bq = 0; bq < 4; ++bq) acc[a][bq] = (f32x4){0.f, 0.f, 0.f, 0.f};

  const int srow = t >> 2;                 // staging row (q=0); q=1 adds 64
  const int scol = (t & 3) * 8;            // k offset within BK=32
  const int ldsb = (t & 192) * 16;         // wave-uniform LDS byte base (q=0); q=1 adds 4096

#pragma unroll 1
  for (int kt = 0; kt < 16; ++kt) {
    const int kb = kt * 32;
    __builtin_amdgcn_global_load_lds(AS1(A + ((size_t)(m0 + srow)) * 512 + kb + scol),
                                     AS3((char*)As + ldsb), 16, 0, 0);
    __builtin_amdgcn_global_load_lds(AS1(A + ((size_t)(m0 + 64 + srow)) * 512 + kb + scol),
                                     AS3((char*)As + 4096 + ldsb), 16, 0, 0);
    __builtin_amdgcn_global_load_lds(AS1(W + ((size_t)(n0 + srow)) * 512 + kb + scol),
                                     AS3((char*)Bs + ldsb), 16, 0, 0);
    __builtin_amdgcn_global_load_lds(AS1(W + ((size_t)(n0 + 64 + srow)) * 512 + kb + scol),
                                     AS3((char*)Bs + 4096 + ldsb), 16, 0, 0);
    __syncthreads();

    bf16x8 af[4], bf[4];
#pragma unroll
    for (int ti = 0; ti < 4; ++ti)
      af[ti] = *(const bf16x8*)(As + (wr + ti * 16 + r16) * 32 + quad * 8);
#pragma unroll
    for (int tj = 0; tj < 4; ++tj)
      bf[tj] = *(const bf16x8*)(Bs + (wc + tj * 16 + r16) * 32 + quad * 8);
#pragma unroll
    for (int ti = 0; ti < 4; ++ti)
#pragma unroll
      for (int tj = 0; tj < 4; ++tj)
        acc[ti][tj] = __builtin_amdgcn_mfma_f32_16x16x32_bf16(af[ti], bf[tj], acc[ti][tj], 0, 0, 0);
    __syncthreads();
  }

#pragma unroll
  for (int ti = 0; ti < 4; ++ti) {
    const int gi0 = m0 + wr + ti * 16 + quad * 4;
#pragma unroll
    for (int tj = 0; tj < 4; ++tj) {
      const int go = n0 + wc + tj * 16 + r16;
      const float bv = bias[go];
#pragma unroll
      for (int r = 0; r < 4; ++r)
        C[(size_t)(gi0 + r) * 512 + go] = acc[ti][tj][r] + bv;
    }
  }
}

// ---------------- K3: t[b,i] = h[b,i,:] . score_w ----------------
__global__ __launch_bounds__(256) void k_tdot(const float* __restrict__ h,
    const float* __restrict__ sw, float* __restrict__ tbuf) {
  const int w = threadIdx.x >> 6, l = threadIdx.x & 63;
  const int rr = blockIdx.x * 4 + w;       // 0..16415
  const int b = rr / L_, i = rr % L_;
  float s = 0.f;
  if (i < N_) {
    const float4* hr = (const float4*)(h + ((size_t)b * N_ + i) * D_);
    const float4* sw4 = (const float4*)sw;
    const float4 a0 = hr[l * 2],     a1 = hr[l * 2 + 1];
    const float4 w0 = sw4[l * 2],    w1 = sw4[l * 2 + 1];
    s = a0.x * w0.x + a0.y * w0.y + a0.z * w0.z + a0.w * w0.w
      + a1.x * w1.x + a1.y * w1.y + a1.z * w1.z + a1.w * w1.w;
  }
#pragma unroll
  for (int off = 32; off > 0; off >>= 1) s += __shfl_down(s, off);
  if (l == 0) tbuf[rr] = s;
}

// ---------------- K4: per-position 4-way softmax scores ----------------
__global__ __launch_bounds__(256) void k_scores(const float* __restrict__ tbuf,
    const float* __restrict__ sb, float4* __restrict__ S) {
  const int idx = blockIdx.x * 256 + threadIdx.x;
  if (idx >= B_ * L_) return;
  const int b = idx / L_, i = idx % L_;
  const float* tb = tbuf + b * L_;
  const float bb = sb[0];
  const float s0 = tb[i] + bb;
  const int j2 = i & ~1;
  const float s1 = (tb[j2] + tb[j2 + 1]) * 0.5f + bb;
  const int j3 = (i / 3) * 3;
  const float s2 = (tb[j3] + tb[j3 + 1] + tb[j3 + 2]) * (1.f / 3.f) + bb;
  const int j4 = i & ~3;
  const float s3 = (tb[j4] + tb[j4 + 1] + tb[j4 + 2] + tb[j4 + 3]) * 0.25f + bb;
  const float m = fmaxf(fmaxf(s0, s1), fmaxf(s2, s3));
  const float e0 = __expf(s0 - m), e1 = __expf(s1 - m), e2 = __expf(s2 - m), e3 = __expf(s3 - m);
  const float inv = 1.f / (e0 + e1 + e2 + e3);
  S[idx] = make_float4(e0 * inv, e1 * inv, e2 * inv, e3 * inv);
}

// ---------------- K5: consensus attention (flash-style, j-chunked, partials) ----------------
__global__ __launch_bounds__(256) void k_attn(const float4* __restrict__ S,
    float4* __restrict__ accnP, float* __restrict__ accdP) {
  __shared__ __align__(16) float4 Sch[CH2];
  const int bx = blockIdx.x;
  const int jc = bx & (JC2 - 1);
  const int rt = (bx >> 5) % RT;
  const int b  = bx / (JC2 * RT);
  const int t = threadIdx.x;
  const float4* Sb = S + (size_t)b * L_;
  const int j0 = jc * CH2;
  const int len = min(CH2, L_ - j0);
  for (int idx = t; idx < len; idx += 256) Sch[idx] = Sb[j0 + idx];
  __syncthreads();
  const int i = rt * 256 + t;
  if (i < L_) {
    const float4 si = Sb[i];
    float l = 0.f, a0 = 0.f, a1 = 0.f, a2 = 0.f, a3 = 0.f;
#pragma unroll 4
    for (int jj = 0; jj < len; ++jj) {
      const float4 v = Sch[jj];
      const float dot = fmaf(si.x, v.x, fmaf(si.y, v.y, fmaf(si.z, v.z, si.w * v.w)));
      const float e = __expf(dot);   // dot in (0,1]; no max-shift needed
      l += e;
      a0 = fmaf(e, v.x, a0); a1 = fmaf(e, v.y, a1);
      a2 = fmaf(e, v.z, a2); a3 = fmaf(e, v.w, a3);
    }
    const size_t base = (size_t)jc * (B_ * L_) + b * L_ + i;
    accnP[base] = make_float4(a0, a1, a2, a3);
    accdP[base] = l;
  }
}

// ---------------- K6: reduce partials -> normalized mixing weights ----------------
__global__ __launch_bounds__(256) void k_reduce(const float4* __restrict__ accnP,
    const float* __restrict__ accdP, float4* __restrict__ wgt) {
  const int idx = blockIdx.x * 256 + threadIdx.x;
  if (idx >= B_ * L_) return;
  float a0 = 0.f, a1 = 0.f, a2 = 0.f, a3 = 0.f, d = 0.f;
#pragma unroll
  for (int jc = 0; jc < JC2; ++jc) {
    const float4 v = accnP[(size_t)jc * (B_ * L_) + idx];
    a0 += v.x; a1 += v.y; a2 += v.z; a3 += v.w;
    d += accdP[(size_t)jc * (B_ * L_) + idx];
  }
  const float inv = 1.f / d;
  wgt[idx] = make_float4(a0 * inv, a1 * inv, a2 * inv, a3 * inv);
}

// ---------------- K7: fuse block reprs (inline pooling) + downsample ----------------
__global__ __launch_bounds__(256) void k_fuse(const float* __restrict__ h,
    const float4* __restrict__ wgt, float* __restrict__ out) {
  const int b = blockIdx.x >> 10, j = blockIdx.x & 1023;
  const int t = threadIdx.x, d = t * 2;
  const int i0 = 4 * j;
  float4 wv[4];
#pragma unroll
  for (int r = 0; r < 4; ++r) wv[r] = wgt[b * L_ + i0 + r];

  const float* hb = h + (size_t)b * N_ * D_;
  float2 hv[4];
#pragma unroll
  for (int q = 0; q < 4; ++q)
    hv[q] = *(const float2*)(hb + (size_t)(i0 + q) * D_ + d);

  // the 4 positions share at most 2 distinct 3-blocks: rows v0..v0+5
  const int v0 = (i0 / 3) * 3;
  float2 w3a = make_float2(0.f, 0.f), w3b = make_float2(0.f, 0.f);
#pragma unroll
  for (int q = 0; q < 3; ++q) {
    const int ra = v0 + q, rb = v0 + 3 + q;
    if (ra < N_) {
      const float2 e = *(const float2*)(hb + (size_t)ra * D_ + d);
      w3a.x += e.x; w3a.y += e.y;
    }
    if (rb < N_) {
      const float2 e = *(const float2*)(hb + (size_t)rb * D_ + d);
      w3b.x += e.x; w3b.y += e.y;
    }
  }
  w3a.x *= (1.f / 3.f); w3a.y *= (1.f / 3.f);
  w3b.x *= (1.f / 3.f); w3b.y *= (1.f / 3.f);

  float2 p4;
  p4.x = (hv[0].x + hv[1].x + hv[2].x + hv[3].x) * 0.25f;
  p4.y = (hv[0].y + hv[1].y + hv[2].y + hv[3].y) * 0.25f;

  float ox = 0.f, oy = 0.f;
#pragma unroll
  for (int r = 0; r < 4; ++r) {
    const int i = i0 + r;
    const float2 p1 = hv[r];
    const int b2 = r & ~1;
    float2 p2;
    p2.x = (hv[b2].x + hv[b2 + 1].x) * 0.5f;
    p2.y = (hv[b2].y + hv[b2 + 1].y) * 0.5f;
    const int r3 = (i / 3) * 3;
    const float2 p3 = (r3 == v0) ? w3a : w3b;
    ox += wv[r].x * p1.x + wv[r].y * p2.x + wv[r].z * p3.x + wv[r].w * p4.x;
    oy += wv[r].x * p1.y + wv[r].y * p2.y + wv[r].z * p3.y + wv[r].w * p4.y;
  }
  float2 o; o.x = ox * 0.25f; o.y = oy * 0.25f;
  *(float2*)(out + (size_t)(b * 1024 + j) * D_ + d) = o;
}

extern "C" void kernel_launch(void* const* d_in, const int* in_sizes, int n_in,
                              void* d_out, int out_size, void* d_ws, size_t ws_size,
                              hipStream_t stream) {
  const int*   x       = (const int*)d_in[0];
  const float* emb     = (const float*)d_in[1];
  const float* conv_w  = (const float*)d_in[2];
  const float* conv_b  = (const float*)d_in[3];
  const float* proj_w  = (const float*)d_in[4];
  const float* proj_b  = (const float*)d_in[5];
  const float* score_w = (const float*)d_in[6];
  const float* score_b = (const float*)d_in[7];
  float* out = (float*)d_out;

  char* ws = (char*)d_ws;
  size_t off = 0;
  __hip_bfloat16* Wbf = (__hip_bfloat16*)(ws + off); off += (size_t)512 * 512 * 2;
  char*           ybase = ws + off;                  off += (size_t)16384 * 512 * 2;
  float*          h   = (float*)(ws + off);          off += (size_t)16384 * 512 * 4;
  float*          tb  = (float*)(ws + off);          off += (size_t)B_ * L_ * 4;
  float4*         S   = (float4*)(ws + off);         off += (size_t)B_ * L_ * 16;
  float4*         wgt = (float4*)(ws + off);         off += (size_t)B_ * L_ * 16;
  // partials alias the y buffer (y is dead after k_gemm; attn runs later on same stream)
  unsigned* y    = (unsigned*)ybase;
  float4*   accnP = (float4*)ybase;                          // JC2*B_*L_*16 = 8.4 MB
  float*    accdP = (float*)(ybase + (size_t)JC2 * B_ * L_ * 16); // +2.1 MB <= 16 MB
  (void)in_sizes; (void)n_in; (void)out_size; (void)ws_size;

  k_cvt<<<1024, 256, 0, stream>>>(proj_w, Wbf);
  k_embconv<<<B_ * N_, 256, 0, stream>>>(x, emb, conv_w, conv_b, y);
  k_gemm<<<dim3(128, 4), 256, 0, stream>>>((const __hip_bfloat16*)y, Wbf, proj_b, h);
  k_tdot<<<(B_ * L_) / 4, 256, 0, stream>>>(h, score_w, tb);
  k_scores<<<(B_ * L_ + 255) / 256, 256, 0, stream>>>(tb, score_b, S);
  k_attn<<<B_ * RT * JC2, 256, 0, stream>>>(S, accnP, accdP);
  k_reduce<<<(B_ * L_ + 255) / 256, 256, 0, stream>>>(accnP, accdP, wgt);
  k_fuse<<<B_ * 1024, 256, 0, stream>>>(h, wgt, out);
}

// Round 3
// 162.466 us; speedup vs baseline: 1.2272x; 1.0729x over previous
//
#include <hip/hip_runtime.h>
#include <hip/hip_bf16.h>

#define B_ 4
#define N_ 4096
#define L_ 4104
#define D_ 512
#define RT 17
#define JC2 32
#define CH2 129

typedef __attribute__((ext_vector_type(8))) short bf16x8;
typedef __attribute__((ext_vector_type(4))) float f32x4;

#define AS1(p) ((__attribute__((address_space(1))) const void*)(p))
#define AS3(p) ((__attribute__((address_space(3))) void*)(p))

__device__ __forceinline__ float bf2f(unsigned short u) {
  union { unsigned u; float f; } c; c.u = ((unsigned)u) << 16; return c.f;
}

// ---------------- K0: fused [proj_w f32->bf16] + [emb gather + depthwise conv -> y bf16] ----------------
__global__ __launch_bounds__(256) void k_pre(const float* __restrict__ pw,
    __hip_bfloat16* __restrict__ Wbf,
    const int* __restrict__ x, const float* __restrict__ emb,
    const float* __restrict__ conv_w, const float* __restrict__ conv_b,
    unsigned* __restrict__ y) {
  const int bx = blockIdx.x;
  const int t = threadIdx.x;
  if (bx < 1024) {                       // cvt: 1024*256 == 512*512
    const int i = bx * 256 + t;
    Wbf[i] = __float2bfloat16(pw[i]);
    return;
  }
  const int row = bx - 1024;             // b*N_ + i
  const int b = row >> 12, i = row & (N_ - 1);
  const int d = t * 2;
  const float4 c0 = ((const float4*)conv_w)[d];
  const float4 c1 = ((const float4*)conv_w)[d + 1];
  const float ca[4] = {c0.x, c0.y, c0.z, c0.w};
  const float cb[4] = {c1.x, c1.y, c1.z, c1.w};
  float2 acc = ((const float2*)conv_b)[t];
#pragma unroll
  for (int k = 0; k < 4; ++k) {
    if (i + k < N_) {
      const int tok = x[b * N_ + i + k];
      const float2 e = *(const float2*)(emb + (size_t)tok * D_ + d);
      acc.x += e.x * ca[k];
      acc.y += e.y * cb[k];
    }
  }
  union { __hip_bfloat16 h[2]; unsigned u; } pk;
  pk.h[0] = __float2bfloat16(acc.x);
  pk.h[1] = __float2bfloat16(acc.y);
  y[(size_t)row * 256 + t] = pk.u;
}

// ---------------- K1: h = y @ proj_w^T + proj_b (bf16 out) + t-partials ----------------
__global__ __launch_bounds__(256) void k_gemm(const __hip_bfloat16* __restrict__ A,
    const __hip_bfloat16* __restrict__ W, const float* __restrict__ bias,
    const float* __restrict__ sw,
    __hip_bfloat16* __restrict__ C, float* __restrict__ tbP) {
  __shared__ __align__(16) __hip_bfloat16 As[128 * 32];
  __shared__ __align__(16) __hip_bfloat16 Bs[128 * 32];
  const int t = threadIdx.x;
  const int m0 = blockIdx.x * 128, n0 = blockIdx.y * 128;
  const int w = t >> 6, l = t & 63;
  const int quad = l >> 4, r16 = l & 15;
  const int wr = (w >> 1) * 64, wc = (w & 1) * 64;

  f32x4 acc[4][4];
#pragma unroll
  for (int a = 0; a < 4; ++a)
#pragma unroll
    for (int bq = 0; bq < 4; ++bq) acc[a][bq] = (f32x4){0.f, 0.f, 0.f, 0.f};

  const int srow = t >> 2;
  const int scol = (t & 3) * 8;
  const int ldsb = (t & 192) * 16;

#pragma unroll 1
  for (int kt = 0; kt < 16; ++kt) {
    const int kb = kt * 32;
    __builtin_amdgcn_global_load_lds(AS1(A + ((size_t)(m0 + srow)) * 512 + kb + scol),
                                     AS3((char*)As + ldsb), 16, 0, 0);
    __builtin_amdgcn_global_load_lds(AS1(A + ((size_t)(m0 + 64 + srow)) * 512 + kb + scol),
                                     AS3((char*)As + 4096 + ldsb), 16, 0, 0);
    __builtin_amdgcn_global_load_lds(AS1(W + ((size_t)(n0 + srow)) * 512 + kb + scol),
                                     AS3((char*)Bs + ldsb), 16, 0, 0);
    __builtin_amdgcn_global_load_lds(AS1(W + ((size_t)(n0 + 64 + srow)) * 512 + kb + scol),
                                     AS3((char*)Bs + 4096 + ldsb), 16, 0, 0);
    __syncthreads();

    bf16x8 af[4], bf[4];
#pragma unroll
    for (int ti = 0; ti < 4; ++ti)
      af[ti] = *(const bf16x8*)(As + (wr + ti * 16 + r16) * 32 + quad * 8);
#pragma unroll
    for (int tj = 0; tj < 4; ++tj)
      bf[tj] = *(const bf16x8*)(Bs + (wc + tj * 16 + r16) * 32 + quad * 8);
#pragma unroll
    for (int ti = 0; ti < 4; ++ti)
#pragma unroll
      for (int tj = 0; tj < 4; ++tj)
        acc[ti][tj] = __builtin_amdgcn_mfma_f32_16x16x32_bf16(af[ti], bf[tj], acc[ti][tj], 0, 0, 0);
    __syncthreads();
  }

  // score_w values for this lane's 4 columns
  float swv[4];
#pragma unroll
  for (int tj = 0; tj < 4; ++tj) swv[tj] = sw[n0 + wc + tj * 16 + r16];

  float tpart[4][4];   // [ti][r]: partial dot over this wave's 64 cols (after shfl)
#pragma unroll
  for (int ti = 0; ti < 4; ++ti) {
    const int gi0 = m0 + wr + ti * 16 + quad * 4;
#pragma unroll
    for (int r = 0; r < 4; ++r) tpart[ti][r] = 0.f;
#pragma unroll
    for (int tj = 0; tj < 4; ++tj) {
      const int go = n0 + wc + tj * 16 + r16;
      const float bv = bias[go];
#pragma unroll
      for (int r = 0; r < 4; ++r) {
        const float cf = acc[ti][tj][r] + bv;
        C[(size_t)(gi0 + r) * 512 + go] = __float2bfloat16(cf);
        tpart[ti][r] = fmaf(cf, swv[tj], tpart[ti][r]);
      }
    }
  }
  // reduce over the 16 col-lanes (r16) inside each quad
#pragma unroll
  for (int ti = 0; ti < 4; ++ti)
#pragma unroll
    for (int r = 0; r < 4; ++r) {
      float v = tpart[ti][r];
      v += __shfl_xor(v, 1); v += __shfl_xor(v, 2);
      v += __shfl_xor(v, 4); v += __shfl_xor(v, 8);
      tpart[ti][r] = v;
    }
  if (r16 == 0) {
    const int p = blockIdx.y * 2 + (w & 1);      // 8 partial planes
#pragma unroll
    for (int ti = 0; ti < 4; ++ti)
#pragma unroll
      for (int r = 0; r < 4; ++r)
        tbP[(size_t)p * 16384 + (m0 + wr + ti * 16 + quad * 4 + r)] = tpart[ti][r];
  }
}

// ---------------- K2: per-position 4-way softmax scores (LDS t-window, sums 8 partials) ----------------
__global__ __launch_bounds__(256) void k_scores(const float* __restrict__ tbP,
    const float* __restrict__ sb, float4* __restrict__ S) {
  __shared__ float tw[262];
  const int b = blockIdx.y;
  const int i0 = blockIdx.x * 256;
  const int t = threadIdx.x;
  for (int idx = t; idx < 262; idx += 256) {
    const int j = i0 - 3 + idx;
    float v = 0.f;
    if (j >= 0 && j < N_) {
      const int rowb = b * N_ + j;
#pragma unroll
      for (int p = 0; p < 8; ++p) v += tbP[(size_t)p * 16384 + rowb];
    }
    tw[idx] = v;
  }
  __syncthreads();
  const int i = i0 + t;
  if (i >= L_) return;
  const float* tb = tw - (i0 - 3);    // tb[j] == tw[j-(i0-3)]
  const float bb = sb[0];
  const float s0 = tb[i] + bb;
  const int j2 = i & ~1;
  const float s1 = (tb[j2] + tb[j2 + 1]) * 0.5f + bb;
  const int j3 = (i / 3) * 3;
  const float s2 = (tb[j3] + tb[j3 + 1] + tb[j3 + 2]) * (1.f / 3.f) + bb;
  const int j4 = i & ~3;
  const float s3 = (tb[j4] + tb[j4 + 1] + tb[j4 + 2] + tb[j4 + 3]) * 0.25f + bb;
  const float m = fmaxf(fmaxf(s0, s1), fmaxf(s2, s3));
  const float e0 = __expf(s0 - m), e1 = __expf(s1 - m), e2 = __expf(s2 - m), e3 = __expf(s3 - m);
  const float inv = 1.f / (e0 + e1 + e2 + e3);
  S[b * L_ + i] = make_float4(e0 * inv, e1 * inv, e2 * inv, e3 * inv);
}

// ---------------- K3: consensus attention (flash-style, j-chunked, partials) ----------------
__global__ __launch_bounds__(256) void k_attn(const float4* __restrict__ S,
    float4* __restrict__ accnP, float* __restrict__ accdP) {
  __shared__ __align__(16) float4 Sch[CH2];
  const int bx = blockIdx.x;
  const int jc = bx & (JC2 - 1);
  const int rt = (bx >> 5) % RT;
  const int b  = bx / (JC2 * RT);
  const int t = threadIdx.x;
  const float4* Sb = S + (size_t)b * L_;
  const int j0 = jc * CH2;
  const int len = min(CH2, L_ - j0);
  for (int idx = t; idx < len; idx += 256) Sch[idx] = Sb[j0 + idx];
  __syncthreads();
  const int i = rt * 256 + t;
  if (i < L_) {
    const float4 si = Sb[i];
    float l = 0.f, a0 = 0.f, a1 = 0.f, a2 = 0.f, a3 = 0.f;
#pragma unroll 4
    for (int jj = 0; jj < len; ++jj) {
      const float4 v = Sch[jj];
      const float dot = fmaf(si.x, v.x, fmaf(si.y, v.y, fmaf(si.z, v.z, si.w * v.w)));
      const float e = __expf(dot);   // dot in (0,1]; no max-shift needed
      l += e;
      a0 = fmaf(e, v.x, a0); a1 = fmaf(e, v.y, a1);
      a2 = fmaf(e, v.z, a2); a3 = fmaf(e, v.w, a3);
    }
    const size_t base = (size_t)jc * (B_ * L_) + b * L_ + i;
    accnP[base] = make_float4(a0, a1, a2, a3);
    accdP[base] = l;
  }
}

// ---------------- K4: reduce partials -> wgt (in-block) + fuse pools + downsample ----------------
__global__ __launch_bounds__(256) void k_fuse(const __hip_bfloat16* __restrict__ h,
    const float4* __restrict__ accnP, const float* __restrict__ accdP,
    float* __restrict__ out) {
  __shared__ __align__(16) float4 wgtS[4];
  const int b = blockIdx.x >> 10, j = blockIdx.x & 1023;
  const int t = threadIdx.x, d = t * 2;
  const int i0 = 4 * j;

  // phase 1: threads 0..127 reduce the 32 j-chunk partials for rows i0..i0+3
  if (t < 128) {
    const int r = t >> 5, jc = t & 31;
    const size_t idx = (size_t)jc * (B_ * L_) + b * L_ + i0 + r;
    float4 nv = accnP[idx];
    float dv = accdP[idx];
#pragma unroll
    for (int m = 16; m >= 1; m >>= 1) {   // xor within 32-lane halves (never crosses)
      nv.x += __shfl_xor(nv.x, m); nv.y += __shfl_xor(nv.y, m);
      nv.z += __shfl_xor(nv.z, m); nv.w += __shfl_xor(nv.w, m);
      dv   += __shfl_xor(dv, m);
    }
    if ((t & 31) == 0) {
      const float inv = 1.f / dv;
      wgtS[r] = make_float4(nv.x * inv, nv.y * inv, nv.z * inv, nv.w * inv);
    }
  }
  __syncthreads();
  float4 wv[4];
#pragma unroll
  for (int r = 0; r < 4; ++r) wv[r] = wgtS[r];

  const __hip_bfloat16* hb = h + (size_t)b * N_ * D_;
  float2 hv[4];
#pragma unroll
  for (int q = 0; q < 4; ++q) {
    const ushort2 u = *(const ushort2*)(hb + (size_t)(i0 + q) * D_ + d);
    hv[q] = make_float2(bf2f(u.x), bf2f(u.y));
  }

  // the 4 positions share at most 2 distinct 3-blocks: rows v0..v0+5
  const int v0 = (i0 / 3) * 3;
  float2 w3a = make_float2(0.f, 0.f), w3b = make_float2(0.f, 0.f);
#pragma unroll
  for (int q = 0; q < 3; ++q) {
    const int ra = v0 + q, rb = v0 + 3 + q;
    if (ra < N_) {
      const ushort2 u = *(const ushort2*)(hb + (size_t)ra * D_ + d);
      w3a.x += bf2f(u.x); w3a.y += bf2f(u.y);
    }
    if (rb < N_) {
      const ushort2 u = *(const ushort2*)(hb + (size_t)rb * D_ + d);
      w3b.x += bf2f(u.x); w3b.y += bf2f(u.y);
    }
  }
  w3a.x *= (1.f / 3.f); w3a.y *= (1.f / 3.f);
  w3b.x *= (1.f / 3.f); w3b.y *= (1.f / 3.f);

  float2 p4;
  p4.x = (hv[0].x + hv[1].x + hv[2].x + hv[3].x) * 0.25f;
  p4.y = (hv[0].y + hv[1].y + hv[2].y + hv[3].y) * 0.25f;

  float ox = 0.f, oy = 0.f;
#pragma unroll
  for (int r = 0; r < 4; ++r) {
    const int i = i0 + r;
    const float2 p1 = hv[r];
    const int b2 = r & ~1;
    float2 p2;
    p2.x = (hv[b2].x + hv[b2 + 1].x) * 0.5f;
    p2.y = (hv[b2].y + hv[b2 + 1].y) * 0.5f;
    const int r3 = (i / 3) * 3;
    const float2 p3 = (r3 == v0) ? w3a : w3b;
    ox += wv[r].x * p1.x + wv[r].y * p2.x + wv[r].z * p3.x + wv[r].w * p4.x;
    oy += wv[r].x * p1.y + wv[r].y * p2.y + wv[r].z * p3.y + wv[r].w * p4.y;
  }
  float2 o; o.x = ox * 0.25f; o.y = oy * 0.25f;
  *(float2*)(out + (size_t)(b * 1024 + j) * D_ + d) = o;
}

extern "C" void kernel_launch(void* const* d_in, const int* in_sizes, int n_in,
                              void* d_out, int out_size, void* d_ws, size_t ws_size,
                              hipStream_t stream) {
  const int*   x       = (const int*)d_in[0];
  const float* emb     = (const float*)d_in[1];
  const float* conv_w  = (const float*)d_in[2];
  const float* conv_b  = (const float*)d_in[3];
  const float* proj_w  = (const float*)d_in[4];
  const float* proj_b  = (const float*)d_in[5];
  const float* score_w = (const float*)d_in[6];
  const float* score_b = (const float*)d_in[7];
  float* out = (float*)d_out;

  char* ws = (char*)d_ws;
  size_t off = 0;
  __hip_bfloat16* Wbf = (__hip_bfloat16*)(ws + off); off += (size_t)512 * 512 * 2;
  char*           ybase = ws + off;                  off += (size_t)16384 * 512 * 2;
  __hip_bfloat16* h   = (__hip_bfloat16*)(ws + off); off += (size_t)16384 * 512 * 2;
  float*          tbP = (float*)(ws + off);          off += (size_t)8 * 16384 * 4;
  float4*         S   = (float4*)(ws + off);         off += (size_t)B_ * L_ * 16;
  // partials alias the y buffer (y dead after k_gemm): 8.4 MB + 2.1 MB <= 16 MB
  unsigned* y     = (unsigned*)ybase;
  float4*   accnP = (float4*)ybase;
  float*    accdP = (float*)(ybase + (size_t)JC2 * B_ * L_ * 16);
  (void)in_sizes; (void)n_in; (void)out_size; (void)ws_size;

  k_pre<<<1024 + B_ * N_, 256, 0, stream>>>(proj_w, Wbf, x, emb, conv_w, conv_b, y);
  k_gemm<<<dim3(128, 4), 256, 0, stream>>>((const __hip_bfloat16*)y, Wbf, proj_b, score_w,
                                           h, tbP);
  k_scores<<<dim3(RT, B_), 256, 0, stream>>>(tbP, score_b, S);
  k_attn<<<B_ * RT * JC2, 256, 0, stream>>>(S, accnP, accdP);
  k_fuse<<<B_ * 1024, 256, 0, stream>>>(h, accnP, accdP, out);
}